// Round 3
// baseline (222.617 us; speedup 1.0000x reference)
//
#include <hip/hip_runtime.h>

// KAN layer fused as one augmented GEMM:
//   out[n][o] = sum_i silu(x[n][i])*scale_base[o][i]
//            + sum_{i,m} basis_m(x[n][i])*scale_sp[o][i]*coef[o][i][m] + bias[o]
// A_aug (8192 x 5376) f16, W_aug (768 x 5376) f16, k = j*768 + i (j=0: silu, j=1..6: basis)
//
// GEMM: 128x128 tile (best LDS-bytes/FLOP), split-K x2 -> grid 768 = exactly
// 3 blocks/CU, XCD-chunked, k-slot XOR swizzle for conflict-free ds_read_b128.

typedef _Float16 f16;
typedef __attribute__((ext_vector_type(4))) _Float16 f16x4;
typedef __attribute__((ext_vector_type(8))) _Float16 f16x8;
typedef __attribute__((ext_vector_type(4))) float f32x4;

#define NTOK 8192
#define DIN 768
#define DOUT 768
#define KAUG 5376        // 7*768
#define BM 128
#define BN 128
#define BK 32
#define KHALF (KAUG / 2) // 2688 elements per K-half
#define KHSTEPS (KHALF / BK)  // 84 steps (even)

typedef __attribute__((address_space(1))) void gvoid;
typedef __attribute__((address_space(3))) void lvoid;

// ---------------- silu + 6 basis values for one x ----------------
__device__ __forceinline__ void spline6(float xv, float* __restrict__ B, float& s) {
  s = xv / (1.0f + __expf(-xv));  // silu
  const float h = 2.0f / 3.0f;
  float Bb[9];
#pragma unroll
  for (int g = 0; g < 9; ++g) {
    float t0 = (float)(g - 3) * h - 1.0f;
    float t1 = (float)(g - 2) * h - 1.0f;
    Bb[g] = (xv >= t0 && xv < t1) ? 1.0f : 0.0f;
  }
#pragma unroll
  for (int p = 1; p <= 3; ++p) {
    float inv = 1.0f / ((float)p * h);
#pragma unroll
    for (int j = 0; j < 8; ++j) {
      if (j < 9 - p) {
        float tj = (float)(j - 3) * h - 1.0f;
        float tjp1 = (float)(j + p + 1 - 3) * h - 1.0f;
        Bb[j] = (xv - tj) * inv * Bb[j] + (tjp1 - xv) * inv * Bb[j + 1];
      }
    }
  }
#pragma unroll
  for (int m = 0; m < 6; ++m) B[m] = Bb[m];
}

// ---------------- Kernel 1: x -> [silu | 6 basis] f16, x4 vectorized ----------------
__global__ __launch_bounds__(256) void build_A(const float* __restrict__ x,
                                               f16* __restrict__ Aa) {
  int idx = (blockIdx.x * 256 + threadIdx.x) * 4;
  float4 xv = *(const float4*)(x + idx);
  int n = idx / DIN;
  int i = idx - n * DIN;

  float B0[6], B1[6], B2[6], B3[6];
  float s0, s1, s2, s3;
  spline6(xv.x, B0, s0);
  spline6(xv.y, B1, s1);
  spline6(xv.z, B2, s2);
  spline6(xv.w, B3, s3);

  size_t base = (size_t)n * KAUG + i;
  f16x4 sv = {(f16)s0, (f16)s1, (f16)s2, (f16)s3};
  *(f16x4*)(Aa + base) = sv;
#pragma unroll
  for (int m = 0; m < 6; ++m) {
    f16x4 bv = {(f16)B0[m], (f16)B1[m], (f16)B2[m], (f16)B3[m]};
    *(f16x4*)(Aa + base + (size_t)(m + 1) * DIN) = bv;
  }
}

// ---------------- Kernel 2: pack weights ----------------
__global__ __launch_bounds__(256) void build_W(const float* __restrict__ sb,
                                               const float* __restrict__ ssp,
                                               const float* __restrict__ coef,
                                               f16* __restrict__ Wa) {
  int idx = blockIdx.x * 256 + threadIdx.x;
  float b = sb[idx];
  float sp = ssp[idx];
  int o = idx / DIN;
  int i = idx - o * DIN;
  size_t base = (size_t)o * KAUG + i;
  Wa[base] = (f16)b;
#pragma unroll
  for (int m = 0; m < 6; ++m)
    Wa[base + (size_t)(m + 1) * DIN] = (f16)(sp * coef[(size_t)idx * 6 + m]);
}

// ---------------- Kernel 2b: out = bias (broadcast), float4 ----------------
__global__ __launch_bounds__(256) void out_init(const float* __restrict__ bias,
                                                float* __restrict__ out) {
  int idx = blockIdx.x * 256 + threadIdx.x;         // over NTOK*DOUT/4
  ((float4*)out)[idx] = ((const float4*)bias)[idx % (DOUT / 4)];
}

// ---------------- Kernel 3: split-K GEMM, atomic accumulate ----------------
// LDS layout: [row][slot s of 8 f16], content LDS[row][s] = G[row][s ^ ((row>>1)&3)].
// global_load_lds dest stays linear (chunk c -> byte c*16); the per-lane GLOBAL
// source is permuted instead (rule: swizzle both sides via the source).
// Read of logical (row, q) -> LDS slot q ^ ((row>>1)&3); 16 lanes spread over 8
// 4-bank groups -> 2 lanes/group = conflict-free.
__global__ __launch_bounds__(256) void kan_gemm(const f16* __restrict__ A,
                                                const f16* __restrict__ W,
                                                float* __restrict__ out) {
  __shared__ alignas(16) f16 As0[BM * BK];  // 8 KB each, 32 KB total
  __shared__ alignas(16) f16 As1[BM * BK];
  __shared__ alignas(16) f16 Bs0[BN * BK];
  __shared__ alignas(16) f16 Bs1[BN * BK];

  const int tid = threadIdx.x;
  const int wave = tid >> 6;
  const int lane = tid & 63;

  // bid%8 = XCD. XCDs 0-3 -> K-half 0, XCDs 4-7 -> K-half 1.
  // Each XCD: 96 blocks = 16 M-panels x 6 N-cols of one K-half (W-half ~= its L2).
  const int bid = blockIdx.x;
  const int xcd = bid & 7;
  const int j = bid >> 3;                  // 0..95
  const int half = xcd >> 2;               // 0,1
  const int t = (xcd & 3) * 96 + j;        // 0..383 tile id
  const int m0 = (t / 6) * BM;
  const int n0 = (t % 6) * BN;
  const size_t k0 = (size_t)half * KHALF;

  const int wm = (wave >> 1) * 64;
  const int wn = (wave & 1) * 64;
  const int r = lane & 15;
  const int q = lane >> 4;

  f32x4 acc[4][4] = {};

  // staging chunk c (16B): row = c>>2, slot = c&3, global kb = slot ^ ((c>>3)&3)
  // ((c>>3)&3 == (row>>1)&3 for slot<4)
  const int c0 = wave * 64 + lane;   // 0..255
  const int c1 = c0 + 256;           // 256..511
  const int row0 = c0 >> 2, kb0 = (c0 & 3) ^ ((c0 >> 3) & 3);
  const int row1 = c1 >> 2, kb1 = (c1 & 3) ^ ((c1 >> 3) & 3);

  const f16* gA0 = A + (size_t)(m0 + row0) * KAUG + k0 + kb0 * 8;
  const f16* gA1 = A + (size_t)(m0 + row1) * KAUG + k0 + kb1 * 8;
  const f16* gB0 = W + (size_t)(n0 + row0) * KAUG + k0 + kb0 * 8;
  const f16* gB1 = W + (size_t)(n0 + row1) * KAUG + k0 + kb1 * 8;

  const int wo = wave * 512;  // f16 units; lane offset (16B/lane) added by HW

#define STAGE(AS, BS, ktile)                                                              \
  do {                                                                                    \
    const int koff = (ktile)*BK;                                                          \
    __builtin_amdgcn_global_load_lds((gvoid*)(gA0 + koff), (lvoid*)(AS + wo), 16, 0, 0);  \
    __builtin_amdgcn_global_load_lds((gvoid*)(gA1 + koff), (lvoid*)(AS + wo + 2048), 16,  \
                                     0, 0);                                               \
    __builtin_amdgcn_global_load_lds((gvoid*)(gB0 + koff), (lvoid*)(BS + wo), 16, 0, 0);  \
    __builtin_amdgcn_global_load_lds((gvoid*)(gB1 + koff), (lvoid*)(BS + wo + 2048), 16,  \
                                     0, 0);                                               \
  } while (0)

  // read swizzle: slot' = q ^ ((r>>1)&3)  (row>>1 & 3 reduces to r>>1 & 3)
  const int sA = (q ^ ((r >> 1) & 3)) * 8;

#define COMPUTE(AS, BS)                                                                   \
  do {                                                                                    \
    f16x8 af[4], bf[4];                                                                   \
    _Pragma("unroll") for (int mi = 0; mi < 4; ++mi) af[mi] =                             \
        *(const f16x8*)&AS[(wm + mi * 16 + r) * BK + sA];                                 \
    _Pragma("unroll") for (int ni = 0; ni < 4; ++ni) bf[ni] =                             \
        *(const f16x8*)&BS[(wn + ni * 16 + r) * BK + sA];                                 \
    _Pragma("unroll") for (int mi = 0; mi < 4; ++mi) _Pragma("unroll") for (int ni = 0;   \
                                                                            ni < 4;      \
                                                                            ++ni)        \
        acc[mi][ni] =                                                                     \
        __builtin_amdgcn_mfma_f32_16x16x32_f16(af[mi], bf[ni], acc[mi][ni], 0, 0, 0);     \
  } while (0)

  STAGE(As0, Bs0, 0);
  __syncthreads();

  for (int kt = 0; kt < KHSTEPS; kt += 2) {  // 84 steps, even
    STAGE(As1, Bs1, kt + 1);
    COMPUTE(As0, Bs0);
    __syncthreads();
    if (kt + 2 < KHSTEPS) STAGE(As0, Bs0, kt + 2);
    COMPUTE(As1, Bs1);
    __syncthreads();
  }

#undef STAGE
#undef COMPUTE

  // epilogue: D mapping col = lane&15, row = q*4 + reg; accumulate into out
#pragma unroll
  for (int mi = 0; mi < 4; ++mi) {
#pragma unroll
    for (int ni = 0; ni < 4; ++ni) {
      const int gcol = n0 + wn + ni * 16 + r;
#pragma unroll
      for (int rg = 0; rg < 4; ++rg) {
        const int grow = m0 + wm + mi * 16 + q * 4 + rg;
        unsafeAtomicAdd(&out[(size_t)grow * DOUT + gcol], acc[mi][ni][rg]);
      }
    }
  }
}

extern "C" void kernel_launch(void* const* d_in, const int* in_sizes, int n_in,
                              void* d_out, int out_size, void* d_ws, size_t ws_size,
                              hipStream_t stream) {
  const float* x = (const float*)d_in[0];           // (4,2048,768)
  const float* coef = (const float*)d_in[1];        // (768,768,6)
  const float* scale_base = (const float*)d_in[2];  // (768,768)
  const float* scale_sp = (const float*)d_in[3];    // (768,768)
  const float* bias = (const float*)d_in[4];        // (768,)
  float* out = (float*)d_out;                       // (8192,768)

  f16* Aa = (f16*)d_ws;                                     // 8192*5376*2 = 88.1 MB
  f16* Wa = (f16*)((char*)d_ws + (size_t)NTOK * KAUG * 2);  // 768*5376*2  = 8.3 MB

  build_A<<<(NTOK * DIN) / (256 * 4), 256, 0, stream>>>(x, Aa);
  build_W<<<(DOUT * DIN) / 256, 256, 0, stream>>>(scale_base, scale_sp, coef, Wa);
  out_init<<<(NTOK * DOUT / 4) / 256, 256, 0, stream>>>(bias, out);
  kan_gemm<<<768, 256, 0, stream>>>(Aa, Wa, out);
}

// Round 5
// 190.495 us; speedup vs baseline: 1.1686x; 1.1686x over previous
//
#include <hip/hip_runtime.h>

// KAN layer fused as one augmented GEMM:
//   out[n][o] = sum_i silu(x[n][i])*scale_base[o][i]
//            + sum_{i,m} basis_m(x[n][i])*scale_sp[o][i]*coef[o][i][m] + bias[o]
// A_aug (8192 x 5376) f16, W_aug (768 x 5376) f16, k = j*768 + i (j=0: silu, j=1..6: basis)
//
// GEMM: 128x192 tile, BK=64, 512 thr (8 waves 2Mx4N, wave tile 64x48), grid=256
// = exactly 1 block/CU. Triple-buffered LDS + counted vmcnt(5) (T3+T4) + setprio
// (T5) + source-side XOR slot swizzle (T2) + XCD-chunked block swizzle (T1).
// Race fix vs R4: explicit lgkmcnt(0) before the end-of-iteration barrier so no
// wave crosses with ds_reads in flight while the next iteration's staging
// overwrites that buffer (only ONE barrier separates read from overwrite).

typedef _Float16 f16;
typedef __attribute__((ext_vector_type(2))) _Float16 f16x2;
typedef __attribute__((ext_vector_type(4))) _Float16 f16x4;
typedef __attribute__((ext_vector_type(8))) _Float16 f16x8;
typedef __attribute__((ext_vector_type(4))) float f32x4;

#define NTOK 8192
#define DIN 768
#define DOUT 768
#define KAUG 5376        // 7*768
#define BM 128
#define BN 192
#define BK 64
#define NKT (KAUG / BK)  // 84 K-tiles
#define ASZ (BM * BK)    // 8192 f16 = 16 KB
#define BSZ (BN * BK)    // 12288 f16 = 24 KB
#define NBLK ((NTOK / BM) * (DOUT / BN))  // 64*4 = 256 blocks

typedef __attribute__((address_space(1))) void gvoid;
typedef __attribute__((address_space(3))) void lvoid;

// ---------------- silu + 6 basis values for one x ----------------
__device__ __forceinline__ void spline6(float xv, float* __restrict__ B, float& s) {
  s = xv / (1.0f + __expf(-xv));  // silu
  const float h = 2.0f / 3.0f;
  float Bb[9];
#pragma unroll
  for (int g = 0; g < 9; ++g) {
    float t0 = (float)(g - 3) * h - 1.0f;
    float t1 = (float)(g - 2) * h - 1.0f;
    Bb[g] = (xv >= t0 && xv < t1) ? 1.0f : 0.0f;
  }
#pragma unroll
  for (int p = 1; p <= 3; ++p) {
    float inv = 1.0f / ((float)p * h);
#pragma unroll
    for (int j = 0; j < 8; ++j) {
      if (j < 9 - p) {
        float tj = (float)(j - 3) * h - 1.0f;
        float tjp1 = (float)(j + p + 1 - 3) * h - 1.0f;
        Bb[j] = (xv - tj) * inv * Bb[j] + (tjp1 - xv) * inv * Bb[j + 1];
      }
    }
  }
#pragma unroll
  for (int m = 0; m < 6; ++m) B[m] = Bb[m];
}

#define NBLK_A ((NTOK * DIN) / 1024)  // 6144 (x4-vectorized, 256 thr)
#define NBLK_W ((DOUT * DIN) / 512)   // 1152 (x2-vectorized, 256 thr)

// ---------------- Kernel 1: fused build of A_aug and W_aug ----------------
__global__ __launch_bounds__(256) void build_AW(const float* __restrict__ x,
                                                const float* __restrict__ sb,
                                                const float* __restrict__ ssp,
                                                const float* __restrict__ coef,
                                                f16* __restrict__ Aa,
                                                f16* __restrict__ Wa) {
  const int b = blockIdx.x;
  if (b < NBLK_A) {
    int idx = (b * 256 + threadIdx.x) * 4;  // 4 consecutive i, same n (DIN%4==0)
    float4 xv = *(const float4*)(x + idx);
    int n = idx / DIN;
    int i = idx - n * DIN;

    float B0[6], B1[6], B2[6], B3[6];
    float s0, s1, s2, s3;
    spline6(xv.x, B0, s0);
    spline6(xv.y, B1, s1);
    spline6(xv.z, B2, s2);
    spline6(xv.w, B3, s3);

    size_t base = (size_t)n * KAUG + i;
    f16x4 sv = {(f16)s0, (f16)s1, (f16)s2, (f16)s3};
    *(f16x4*)(Aa + base) = sv;
#pragma unroll
    for (int m = 0; m < 6; ++m) {
      f16x4 bv = {(f16)B0[m], (f16)B1[m], (f16)B2[m], (f16)B3[m]};
      *(f16x4*)(Aa + base + (size_t)(m + 1) * DIN) = bv;
    }
  } else {
    int idx2 = ((b - NBLK_A) * 256 + threadIdx.x) * 2;  // (o,i) and (o,i+1)
    float2 bb = *(const float2*)(sb + idx2);
    float2 pp = *(const float2*)(ssp + idx2);
    int o = idx2 / DIN;
    int i = idx2 - o * DIN;
    size_t base = (size_t)o * KAUG + i;
    f16x2 w0 = {(f16)bb.x, (f16)bb.y};
    *(f16x2*)(Wa + base) = w0;
    float4 c0 = *(const float4*)(coef + (size_t)idx2 * 6);
    float4 c1 = *(const float4*)(coef + (size_t)idx2 * 6 + 4);
    float4 c2 = *(const float4*)(coef + (size_t)idx2 * 6 + 8);
    float ma[6] = {c0.x, c0.y, c0.z, c0.w, c1.x, c1.y};
    float mb[6] = {c1.z, c1.w, c2.x, c2.y, c2.z, c2.w};
#pragma unroll
    for (int m = 0; m < 6; ++m) {
      f16x2 wv = {(f16)(pp.x * ma[m]), (f16)(pp.y * mb[m])};
      *(f16x2*)(Wa + base + (size_t)(m + 1) * DIN) = wv;
    }
  }
}

// ---------------- Kernel 2: GEMM C = A_aug * W_aug^T + bias ----------------
// LDS content: buf[row][slot] = G[row][slot ^ (row&7)] (slot = 8-f16 group of K).
// global_load_lds dest linear (chunk c -> 16B at c*16); per-lane GLOBAL src is
// pre-swizzled. Reads apply the same XOR -> conflict-free (2 lanes/bank = free).
// Schedule per K-tile t (3-buf: prefetch target never concurrently read):
//   ph0: ds_read af/bf[kh=0] | stage B(t+2) | 12 MFMA   -- barrier
//   ph1: ds_read af/bf[kh=1] | stage A(t+2) | 12 MFMA | lgkmcnt(0) vmcnt(5) -- barrier
// vmcnt(5): the 5 newest in-flight loads are exactly {B(t+2)[3], A(t+2)[2]};
// everything older (incl. all of tile t+1) has landed (FIFO vmcnt, m135).
__global__ __launch_bounds__(512, 2) void kan_gemm(const f16* __restrict__ A,
                                                   const f16* __restrict__ W,
                                                   const float* __restrict__ bias,
                                                   float* __restrict__ out) {
  __shared__ alignas(16) f16 As[3 * ASZ];  // 48 KB
  __shared__ alignas(16) f16 Bs[3 * BSZ];  // 72 KB  (120 KB total, 1 block/CU)

  const int tid = threadIdx.x;
  const int wave = tid >> 6;
  const int lane = tid & 63;

  // XCD-chunked swizzle: 256 % 8 == 0 -> bijective. Each XCD: 8 M-panels x 4 cols.
  const int bid = blockIdx.x;
  const int wg = (bid & 7) * (NBLK / 8) + (bid >> 3);
  const int m0 = (wg >> 2) * BM;
  const int n0 = (wg & 3) * BN;

  const int wm = (wave >> 2) * 64;  // 2 M-waves
  const int wn = (wave & 3) * 48;   // 4 N-waves
  const int r = lane & 15;
  const int q = lane >> 4;
  const int r7 = r & 7;

  f32x4 acc[4][3] = {};

  // ---- staging source pointers (chunk c: row = c>>3, lds slot = c&7,
  //      global slot = (c&7) ^ (row&7)) ----
  const int cA0 = tid, cA1 = tid + 512;
  const int cB0 = tid, cB1 = tid + 512, cB2 = tid + 1024;
  const f16* gA0 = A + (size_t)(m0 + (cA0 >> 3)) * KAUG + ((cA0 & 7) ^ ((cA0 >> 3) & 7)) * 8;
  const f16* gA1 = A + (size_t)(m0 + (cA1 >> 3)) * KAUG + ((cA1 & 7) ^ ((cA1 >> 3) & 7)) * 8;
  const f16* gB0 = W + (size_t)(n0 + (cB0 >> 3)) * KAUG + ((cB0 & 7) ^ ((cB0 >> 3) & 7)) * 8;
  const f16* gB1 = W + (size_t)(n0 + (cB1 >> 3)) * KAUG + ((cB1 & 7) ^ ((cB1 >> 3) & 7)) * 8;
  const f16* gB2 = W + (size_t)(n0 + (cB2 >> 3)) * KAUG + ((cB2 & 7) ^ ((cB2 >> 3) & 7)) * 8;
  // wave-uniform LDS dests (f16 units); HW adds lane*16B
  const int dA0 = wave * 512, dA1 = 4096 + wave * 512;
  const int dB0 = wave * 512, dB1 = 4096 + wave * 512, dB2 = 8192 + wave * 512;

#define STAGE_B(bufi, kt)                                                                  \
  do {                                                                                     \
    const int ko = (kt)*BK;                                                                \
    f16* bb_ = Bs + (bufi)*BSZ;                                                            \
    __builtin_amdgcn_global_load_lds((gvoid*)(gB0 + ko), (lvoid*)(bb_ + dB0), 16, 0, 0);   \
    __builtin_amdgcn_global_load_lds((gvoid*)(gB1 + ko), (lvoid*)(bb_ + dB1), 16, 0, 0);   \
    __builtin_amdgcn_global_load_lds((gvoid*)(gB2 + ko), (lvoid*)(bb_ + dB2), 16, 0, 0);   \
  } while (0)

#define STAGE_A(bufi, kt)                                                                  \
  do {                                                                                     \
    const int ko = (kt)*BK;                                                                \
    f16* ab_ = As + (bufi)*ASZ;                                                            \
    __builtin_amdgcn_global_load_lds((gvoid*)(gA0 + ko), (lvoid*)(ab_ + dA0), 16, 0, 0);   \
    __builtin_amdgcn_global_load_lds((gvoid*)(gA1 + ko), (lvoid*)(ab_ + dA1), 16, 0, 0);   \
  } while (0)

  // one phase: ds_read the kh-half subtile, issue stage, MFMA cluster
#define PH(bufi, kh, STAGE_STMT)                                                           \
  do {                                                                                     \
    const f16* Ab = As + (bufi)*ASZ;                                                       \
    const f16* Bb = Bs + (bufi)*BSZ;                                                       \
    const int sl = (((kh)*4 + q) ^ r7) * 8;                                                \
    f16x8 af[4], bf[3];                                                                    \
    _Pragma("unroll") for (int mi = 0; mi < 4; ++mi) af[mi] =                              \
        *(const f16x8*)&Ab[(wm + mi * 16 + r) * BK + sl];                                  \
    _Pragma("unroll") for (int ni = 0; ni < 3; ++ni) bf[ni] =                              \
        *(const f16x8*)&Bb[(wn + ni * 16 + r) * BK + sl];                                  \
    STAGE_STMT;                                                                            \
    __builtin_amdgcn_s_setprio(1);                                                         \
    _Pragma("unroll") for (int mi = 0; mi < 4; ++mi)                                       \
        _Pragma("unroll") for (int ni = 0; ni < 3; ++ni) acc[mi][ni] =                     \
        __builtin_amdgcn_mfma_f32_16x16x32_f16(af[mi], bf[ni], acc[mi][ni], 0, 0, 0);      \
    __builtin_amdgcn_s_setprio(0);                                                         \
  } while (0)

  // end-of-iteration fence: ds_reads of this iter complete (race fix) + staged
  // tile t+1 landed (counted vmcnt, never 0 in loop), then barrier.
#define FENCE_BAR(VMC)                                            \
  do {                                                            \
    asm volatile("s_waitcnt lgkmcnt(0) vmcnt(" #VMC ")" ::: "memory"); \
    __builtin_amdgcn_sched_barrier(0);                            \
    __builtin_amdgcn_s_barrier();                                 \
  } while (0)

#define MID_BAR()                                                 \
  do {                                                            \
    asm volatile("s_waitcnt lgkmcnt(0)" ::: "memory");            \
    __builtin_amdgcn_sched_barrier(0);                            \
    __builtin_amdgcn_s_barrier();                                 \
  } while (0)

  // prologue: stage tiles 0 and 1 (issue order matters for vmcnt accounting)
  STAGE_B(0, 0);
  STAGE_A(0, 0);
  STAGE_B(1, 1);
  STAGE_A(1, 1);
  FENCE_BAR(5);  // tile 0 fully landed (5 newest = tile 1's loads)

  for (int t = 0; t < NKT - 2; ++t) {  // t = 0..81, stages t+2 in [2,83]
    const int rb = t % 3;
    const int pb = (t + 2) % 3;
    PH(rb, 0, STAGE_B(pb, t + 2));
    MID_BAR();
    PH(rb, 1, STAGE_A(pb, t + 2));
    FENCE_BAR(5);  // tile t+1 fully landed
  }
  {  // t = 82: no staging; drain for final tile
    const int rb = (NKT - 2) % 3;
    PH(rb, 0, (void)0);
    MID_BAR();
    PH(rb, 1, (void)0);
    FENCE_BAR(0);
  }
  {  // t = 83
    const int rb = (NKT - 1) % 3;
    PH(rb, 0, (void)0);
    PH(rb, 1, (void)0);
  }

#undef STAGE_A
#undef STAGE_B
#undef PH
#undef FENCE_BAR
#undef MID_BAR

  // epilogue: D mapping col = lane&15, row = q*4 + reg; bias fused
#pragma unroll
  for (int mi = 0; mi < 4; ++mi) {
#pragma unroll
    for (int ni = 0; ni < 3; ++ni) {
      const int gcol = n0 + wn + ni * 16 + r;
      const float bv = bias[gcol];
#pragma unroll
      for (int rg = 0; rg < 4; ++rg) {
        const int grow = m0 + wm + mi * 16 + q * 4 + rg;
        out[(size_t)grow * DOUT + gcol] = acc[mi][ni][rg] + bv;
      }
    }
  }
}

extern "C" void kernel_launch(void* const* d_in, const int* in_sizes, int n_in,
                              void* d_out, int out_size, void* d_ws, size_t ws_size,
                              hipStream_t stream) {
  const float* x = (const float*)d_in[0];           // (4,2048,768)
  const float* coef = (const float*)d_in[1];        // (768,768,6)
  const float* scale_base = (const float*)d_in[2];  // (768,768)
  const float* scale_sp = (const float*)d_in[3];    // (768,768)
  const float* bias = (const float*)d_in[4];        // (768,)
  float* out = (float*)d_out;                       // (8192,768)

  f16* Aa = (f16*)d_ws;                                     // 8192*5376*2 = 88.1 MB
  f16* Wa = (f16*)((char*)d_ws + (size_t)NTOK * KAUG * 2);  // 768*5376*2  = 8.3 MB

  build_AW<<<NBLK_A + NBLK_W, 256, 0, stream>>>(x, scale_base, scale_sp, coef, Aa, Wa);
  kan_gemm<<<NBLK, 512, 0, stream>>>(Aa, Wa, bias, out);
}